// Round 4
// baseline (17437.059 us; speedup 1.0000x reference)
//
#include <hip/hip_runtime.h>

// HiPPO-LegS forward scan: x_t = A_t x_{t-1} + B_t * inp[t,b], out[t,b,:] = x_t
// L=1024, BATCH=256, N=256, fp32. A_t lower-triangular (upper ~1e-13 junk, skipped).
//
// Round 4: kill the serialized memory round-trips.
// R3 counters: VGPR=56 -> compiler consumed the 16 A-chunks in small load/wait
// batches => multiple exposed latencies per step (19.6K cyc vs ~1.7K VALU).
//  - asm "+v" pin on all 16 f32x4 chunks: forces 16 loads in flight, ONE vmcnt wait.
//  - depth-1 pipeline IN PLACE: after the FMA loop consumes ab, immediately
//    re-issue step t+1's loads into the same registers; they stay in flight
//    across butterfly + LDS write + lgkm-only barrier. Zero extra VGPRs.
//  - inactive (upper-tri) chunks zero-initialized once, never reloaded.
//  - non-temporal output stores: stop the 262MB out-stream from thrashing L3,
//    so A_t (268MB cycle) actually caches -> lower miss latency + HBM fetch.

typedef float f32x4 __attribute__((ext_vector_type(4)));

#define LSTEPS   1024
#define BATCH    256
#define NDIM     256
#define NWG      128
#define BB       2
#define THREADS  1024
#define XPLANE   260   // floats per batch plane (256 + 4 pad; 16B-aligned rows)

__global__ __launch_bounds__(THREADS, 4)
void hippo_scan(const float* __restrict__ inp,   // (L, BATCH)
                const float* __restrict__ A,     // (L, N, N)
                const float* __restrict__ Bst,   // (L, N)
                float* __restrict__ out)         // (L, BATCH, N)
{
    __shared__ __align__(16) float xs[2][BB][XPLANE];

    const int T     = threadIdx.x;
    const int g     = T >> 4;        // 0..63 row-group (4 rows)
    const int s     = T & 15;        // 0..15 k-segment
    const int rbase = g * 4;
    const int b0    = blockIdx.x * BB;
    const int sel1  = (s >> 1) & 1;
    const int sel2  = (s >> 2) & 1;
    const int rowOwn = rbase + (sel1 | (sel2 << 1));
    const int bOwn   = s & 1;
    const bool writer = (s < 8);

    for (int i = T; i < 2 * BB * XPLANE; i += THREADS)
        ((float*)xs)[i] = 0.f;

    float bst_c = Bst[rowOwn];
    float inp_c = inp[b0 + bOwn];
    float* outp = out + (size_t)(b0 + bOwn) * NDIM + rowOwn;

    // per-thread A base; chunk (j,i) at At + i*NDIM + j*64
    const float* At = A + (size_t)rbase * NDIM + s * 4;

    // prologue: issue step-0 loads (masked; inactive chunks stay zero forever)
    f32x4 ab[4][4];
#pragma unroll
    for (int j = 0; j < 4; ++j) {
        const int k0 = j * 64 + s * 4;
#pragma unroll
        for (int i = 0; i < 4; ++i) {
            ab[j][i] = f32x4{0.f, 0.f, 0.f, 0.f};
            if (k0 <= rbase + i)
                ab[j][i] = *(const f32x4*)(At + i * NDIM + j * 64);
        }
    }

    __syncthreads();   // xs init visible (full drain once at t=0 is fine)

    for (int t = 0; t < LSTEPS; ++t) {
        const int cur = t & 1;

        // x reads issue first (lgkm counter; overlaps the vm wait below)
        f32x4 xv0[4], xv1[4];
#pragma unroll
        for (int j = 0; j < 4; ++j) {
            const int k0 = j * 64 + s * 4;
            xv0[j] = *(const f32x4*)&xs[cur][0][k0];
            xv1[j] = *(const f32x4*)&xs[cur][1][k0];
        }

        // pin: all 16 in-flight A loads must be materialized HERE -> single
        // s_waitcnt vmcnt(0), 16-deep MLP, no load/consume interleave.
        asm volatile("" :
            "+v"(ab[0][0]), "+v"(ab[0][1]), "+v"(ab[0][2]), "+v"(ab[0][3]),
            "+v"(ab[1][0]), "+v"(ab[1][1]), "+v"(ab[1][2]), "+v"(ab[1][3]),
            "+v"(ab[2][0]), "+v"(ab[2][1]), "+v"(ab[2][2]), "+v"(ab[2][3]),
            "+v"(ab[3][0]), "+v"(ab[3][1]), "+v"(ab[3][2]), "+v"(ab[3][3]));

        float acc[4][BB];
#pragma unroll
        for (int i = 0; i < 4; ++i)
#pragma unroll
            for (int b = 0; b < BB; ++b) acc[i][b] = 0.f;

#pragma unroll
        for (int j = 0; j < 4; ++j) {
#pragma unroll
            for (int i = 0; i < 4; ++i) {
                const f32x4 a = ab[j][i];
                acc[i][0] = fmaf(a[0], xv0[j][0], acc[i][0]);
                acc[i][0] = fmaf(a[1], xv0[j][1], acc[i][0]);
                acc[i][0] = fmaf(a[2], xv0[j][2], acc[i][0]);
                acc[i][0] = fmaf(a[3], xv0[j][3], acc[i][0]);
                acc[i][1] = fmaf(a[0], xv1[j][0], acc[i][1]);
                acc[i][1] = fmaf(a[1], xv1[j][1], acc[i][1]);
                acc[i][1] = fmaf(a[2], xv1[j][2], acc[i][1]);
                acc[i][1] = fmaf(a[3], xv1[j][3], acc[i][1]);
            }
        }

        // re-issue step t+1 loads into the SAME registers (WAR after last FMA
        // use -> regalloc reuses in place). They stay in flight across the
        // butterfly + LDS write + lgkm-only barrier (~depth-1 pipeline).
        {
            const float* An = At + (t + 1 < LSTEPS ? NDIM * NDIM : 0);
#pragma unroll
            for (int j = 0; j < 4; ++j) {
                const int k0 = j * 64 + s * 4;
#pragma unroll
                for (int i = 0; i < 4; ++i) {
                    if (k0 <= rbase + i)
                        ab[j][i] = *(const f32x4*)(An + i * NDIM + j * 64);
                }
            }
            At = An;
        }

        // prefetch next-step scalars
        const int tn = (t + 1 < LSTEPS) ? t + 1 : t;
        const float bst_n = Bst[tn * NDIM + rowOwn];
        const float inp_n = inp[tn * BATCH + b0 + bOwn];

        // 4-stage butterfly: sums 16 k-segments, redistributes to (rowOwn,bOwn)
        float c[4];
#pragma unroll
        for (int i = 0; i < 4; ++i) {
            const float keep = bOwn ? acc[i][1] : acc[i][0];
            const float send = bOwn ? acc[i][0] : acc[i][1];
            c[i] = keep + __shfl_xor(send, 1);
        }
        float d[2];
#pragma unroll
        for (int m = 0; m < 2; ++m) {
            const float keep = c[2 * m + sel1];
            const float send = c[2 * m + (1 - sel1)];
            d[m] = keep + __shfl_xor(send, 2);
        }
        const float e = d[sel2] + __shfl_xor(d[1 - sel2], 4);
        float v = e + __shfl_xor(e, 8);

        v = fmaf(inp_c, bst_c, v);

        if (writer) {
            xs[cur ^ 1][bOwn][rowOwn] = v;       // state for step t+1
            __builtin_nontemporal_store(v, outp); // out[t][b0+bOwn][rowOwn]
        }
        outp += BATCH * NDIM;
        bst_c = bst_n;
        inp_c = inp_n;

        // drain LDS only; A prefetch loads stay in flight across the barrier
        asm volatile("s_waitcnt lgkmcnt(0)" ::: "memory");
        __builtin_amdgcn_s_barrier();
        asm volatile("" ::: "memory");
    }
}

extern "C" void kernel_launch(void* const* d_in, const int* in_sizes, int n_in,
                              void* d_out, int out_size, void* d_ws, size_t ws_size,
                              hipStream_t stream) {
    const float* inp = (const float*)d_in[0];  // (L, BATCH) f32
    const float* A   = (const float*)d_in[1];  // (L, N, N)  f32
    const float* Bst = (const float*)d_in[2];  // (L, N)     f32
    float* out = (float*)d_out;                // (L, BATCH, N) f32
    hipLaunchKernelGGL(hippo_scan, dim3(NWG), dim3(THREADS), 0, stream,
                       inp, A, Bst, out);
}

// Round 5
// 6901.424 us; speedup vs baseline: 2.5266x; 2.5266x over previous
//
#include <hip/hip_runtime.h>

// HiPPO-LegS forward scan: x_t = A_t x_{t-1} + B_t * inp[t,b], out[t,b,:] = x_t
// L=1024, BATCH=256, N=256, fp32. A_t lower-triangular (upper ~1e-13 junk).
//
// Round 5:
//  - REVERT non-temporal store (R4: 93x write amplification, 24.5GB -> write-bound).
//  - BB=1, 256 WGs -> all 256 CUs active (R3/R4 idled half the chip).
//  - Register pressure halved (~100 VGPR) + __launch_bounds__(1024,2) (cap 256,
//    free since grid==#CUs => 1 WG/CU regardless) so the 16-quad pin can hold.
//  - Balanced triangle: g owns rows {2g, 2g+1, 254-2g, 255-2g} -> every thread
//    ~8-10 active A chunks (was 1..16 skewed; slowest wave gated the barrier).
//  - asm "+v" pin on the 16 f32x4 A chunks -> one vmcnt wait, 16-deep MLP;
//    in-place WAR re-issue of step t+1 loads flies across the lgkm-only barrier.

typedef float f32x4 __attribute__((ext_vector_type(4)));

#define LSTEPS   1024
#define BATCH    256
#define NDIM     256
#define NWG      256
#define THREADS  1024
#define XPLANE   260   // 256 + 4 pad floats, keeps 16B alignment

__global__ __launch_bounds__(THREADS, 2)
void hippo_scan(const float* __restrict__ inp,   // (L, BATCH)
                const float* __restrict__ A,     // (L, N, N)
                const float* __restrict__ Bst,   // (L, N)
                float* __restrict__ out)         // (L, BATCH, N)
{
    __shared__ __align__(16) float xs[2][XPLANE];

    const int T = threadIdx.x;
    const int g = T >> 4;        // 0..63
    const int s = T & 15;        // 0..15
    const int b = blockIdx.x;    // one batch per WG

    int rows[4];
    rows[0] = 2 * g;
    rows[1] = 2 * g + 1;
    rows[2] = 254 - 2 * g;
    rows[3] = 255 - 2 * g;

    const int sel0 = s & 1;
    const int sel1 = (s >> 1) & 1;
    const int rowOwn = rows[sel0 + 2 * sel1];
    const bool writer = (s < 4);   // one writer per row

    for (int i = T; i < 2 * XPLANE; i += THREADS) ((float*)xs)[i] = 0.f;

    float bst_c = Bst[rowOwn];     // Bst[0][rowOwn]
    float inp_c = inp[b];          // inp[0][b]
    float* outp = out + (size_t)b * NDIM + rowOwn;

    // A chunk (j,i) at At + rows[i]*NDIM + j*64 (+ s*4 folded into At)
    const float* At = A + s * 4;

    // prologue: step-0 loads; inactive (upper-tri) chunks stay zero forever
    f32x4 ab[4][4];
#pragma unroll
    for (int j = 0; j < 4; ++j) {
        const int k0 = j * 64 + s * 4;
#pragma unroll
        for (int i = 0; i < 4; ++i) {
            ab[j][i] = f32x4{0.f, 0.f, 0.f, 0.f};
            if (k0 <= rows[i])
                ab[j][i] = *(const f32x4*)(At + rows[i] * NDIM + j * 64);
        }
    }

    __syncthreads();   // xs init visible

    for (int t = 0; t < LSTEPS; ++t) {
        const int cur = t & 1;

        // x reads (lgkm counter; overlap the vm wait from the pin)
        f32x4 xv[4];
#pragma unroll
        for (int j = 0; j < 4; ++j)
            xv[j] = *(const f32x4*)&xs[cur][j * 64 + s * 4];

        // pin: all 16 in-flight A loads materialize here -> single vmcnt wait
        asm volatile("" :
            "+v"(ab[0][0]), "+v"(ab[0][1]), "+v"(ab[0][2]), "+v"(ab[0][3]),
            "+v"(ab[1][0]), "+v"(ab[1][1]), "+v"(ab[1][2]), "+v"(ab[1][3]),
            "+v"(ab[2][0]), "+v"(ab[2][1]), "+v"(ab[2][2]), "+v"(ab[2][3]),
            "+v"(ab[3][0]), "+v"(ab[3][1]), "+v"(ab[3][2]), "+v"(ab[3][3]));

        float acc[4] = {0.f, 0.f, 0.f, 0.f};
#pragma unroll
        for (int j = 0; j < 4; ++j) {
#pragma unroll
            for (int i = 0; i < 4; ++i) {
                const f32x4 a = ab[j][i];
                acc[i] = fmaf(a[0], xv[j][0], acc[i]);
                acc[i] = fmaf(a[1], xv[j][1], acc[i]);
                acc[i] = fmaf(a[2], xv[j][2], acc[i]);
                acc[i] = fmaf(a[3], xv[j][3], acc[i]);
            }
        }

        // re-issue step t+1 loads into the SAME registers (WAR in place);
        // they stay in flight across butterfly + store + lgkm-only barrier
        {
            const float* An = At + (t + 1 < LSTEPS ? NDIM * NDIM : 0);
#pragma unroll
            for (int j = 0; j < 4; ++j) {
                const int k0 = j * 64 + s * 4;
#pragma unroll
                for (int i = 0; i < 4; ++i)
                    if (k0 <= rows[i])
                        ab[j][i] = *(const f32x4*)(An + rows[i] * NDIM + j * 64);
            }
            At = An;
        }

        // prefetch next-step scalars
        const int tn = (t + 1 < LSTEPS) ? t + 1 : t;
        const float bst_n = Bst[tn * NDIM + rowOwn];
        const float inp_n = inp[tn * BATCH + b];

        // 4-stage butterfly over the 16-lane group: sums 16 k-segments and
        // redistributes so lane s holds row rows[sel0+2*sel1].
        const float c0 = (sel0 ? acc[1] : acc[0]) + __shfl_xor(sel0 ? acc[0] : acc[1], 1);
        const float c1 = (sel0 ? acc[3] : acc[2]) + __shfl_xor(sel0 ? acc[2] : acc[3], 1);
        float d = (sel1 ? c1 : c0) + __shfl_xor(sel1 ? c0 : c1, 2);
        d += __shfl_xor(d, 4);
        d += __shfl_xor(d, 8);

        const float v = fmaf(inp_c, bst_c, d);

        if (writer) {
            xs[cur ^ 1][rowOwn] = v;   // state for step t+1
            *outp = v;                 // out[t][b][rowOwn] (normal cached store)
        }
        outp += BATCH * NDIM;
        bst_c = bst_n;
        inp_c = inp_n;

        // drain LDS only; A prefetch loads stay in flight across the barrier
        asm volatile("s_waitcnt lgkmcnt(0)" ::: "memory");
        __builtin_amdgcn_s_barrier();
        asm volatile("" ::: "memory");
    }
}

extern "C" void kernel_launch(void* const* d_in, const int* in_sizes, int n_in,
                              void* d_out, int out_size, void* d_ws, size_t ws_size,
                              hipStream_t stream) {
    const float* inp = (const float*)d_in[0];  // (L, BATCH) f32
    const float* A   = (const float*)d_in[1];  // (L, N, N)  f32
    const float* Bst = (const float*)d_in[2];  // (L, N)     f32
    float* out = (float*)d_out;                // (L, BATCH, N) f32
    hipLaunchKernelGGL(hippo_scan, dim3(NWG), dim3(THREADS), 0, stream,
                       inp, A, Bst, out);
}

// Round 6
// 3378.030 us; speedup vs baseline: 5.1619x; 2.0430x over previous
//
#include <hip/hip_runtime.h>

// HiPPO-LegS forward scan: x_t = A_t x_{t-1} + B_t*inp[t,b]; out[t,b,:]=x_t.
// L=1024, BATCH=256, N=256, fp32. A_t lower-triangular.
//
// Round 6: A streamed via global_load_lds into a packed-triangle LDS tile
// (133KB), split into two k-halves with rolling overwrite + counted vmcnt.
// Registers hold NO A data -> the 128-VGPR cap (16 waves/CU) stops mattering.
//
// LDS layout (floats):
//   [0 .. 6208*4)                H0: chunks (r, m<32), row-packed, m ascending
//   [6208*4 .. 8320*4)           H1: chunks (r, m>=32), rows 128..255
//   [XSOFF .. XSOFF+512)         xs[2][256] ping-pong state
// chunk = 16B = 4 floats of one row (k = 4m..4m+3), present iff 4m <= r.
//
// Per-step schedule (per wave), 3 barriers:
//   ph0 FMA (H0^t) ; vmcnt(0)->lgkm->BAR ; issue H0^{t+1}(7) ;
//   scal loads + out[t-1] full-line store ;
//   ph1 FMA (H1^t) ; lgkm->BAR ; issue H1^{t+1}(3) ;
//   butterfly -> x-update ; vmcnt(3) [newest 3 = H1^{t+1}] -> lgkm -> BAR.
// Every vmcnt wait precedes a barrier that precedes the consume (m201 rule),
// so cross-wave DMA visibility is guaranteed.

typedef float f32x4 __attribute__((ext_vector_type(4)));

#define LSTEPS   1024
#define BATCH    256
#define NDIM     256
#define NWG      256
#define THREADS  1024
#define H0C      6208      // 16B chunks in H0 (= 97*64 exactly)
#define H1C      2112      // = 33*64 exactly
#define H0SLOTS  97        // 1KB wave-issue slots
#define H1SLOTS  33
#define H0ISS    7         // issues per wave (uniform, dup-padded)
#define H1ISS    3
#define XSOFF    ((H0C + H1C) * 4)          // 33280 floats
#define SMEM_BYTES ((XSOFF + 2 * NDIM) * 4) // 135168 B

__device__ __forceinline__ int rs0(int r) {  // chunks before row r in H0, r in [0,256]
    if (r >= 128) return 2112 + (r - 128) * 32;
    int q = r >> 2;
    return 2 * q * (q - 1) + (r - (q << 2)) * q + r;
}
__device__ __forceinline__ int rs1(int r) {  // chunks before row r in H1, r in [128,256]
    int q = r >> 2;
    int S = 2 * q * (q - 1) + (r - (q << 2)) * q;   // sum floor(r'/4), r' < r
    return S - 1984 - 31 * (r - 128);
}
__device__ __forceinline__ int frow0(int c) {  // row containing H0 chunk c
    int lo = 0, hi = 255;
    while (lo < hi) { int mid = (lo + hi + 1) >> 1; if (rs0(mid) <= c) lo = mid; else hi = mid - 1; }
    return lo;
}
__device__ __forceinline__ int frow1(int c) {  // row containing H1 chunk c
    int lo = 128, hi = 255;
    while (lo < hi) { int mid = (lo + hi + 1) >> 1; if (rs1(mid) <= c) lo = mid; else hi = mid - 1; }
    return lo;
}
__device__ __forceinline__ void gload_lds16(const float* g, float* l) {
    __builtin_amdgcn_global_load_lds(
        (const __attribute__((address_space(1))) void*)g,
        (__attribute__((address_space(3))) void*)l, 16, 0, 0);
}

__global__ __launch_bounds__(THREADS)
void hippo_scan(const float* __restrict__ inp,   // (L, BATCH)
                const float* __restrict__ A,     // (L, N, N)
                const float* __restrict__ Bst,   // (L, N)
                float* __restrict__ out)         // (L, BATCH, N)
{
    extern __shared__ float smem[];
    float* Ab = smem;

    const int T    = threadIdx.x;
    const int lane = T & 63;
    const int wave = T >> 6;
    const int g    = T >> 4;       // 0..63 row-group
    const int s    = T & 15;       // 0..15 k-segment
    const int b    = blockIdx.x;

    int rows[4] = {2 * g, 2 * g + 1, 254 - 2 * g, 255 - 2 * g};
    const int sel0 = s & 1, sel1 = (s >> 1) & 1;
    const int rowOwn = rows[sel0 + 2 * sel1];
    const bool writer = (s < 4);

    // FMA-read bases (float offsets) + per-row max active chunk index
    int a0base[4], mmax[4];
#pragma unroll
    for (int i = 0; i < 4; ++i) { a0base[i] = rs0(rows[i]) * 4; mmax[i] = rows[i] >> 2; }
    int a1base[2];
    a1base[0] = (H0C + rs1(rows[2]) - 32) * 4;
    a1base[1] = (H0C + rs1(rows[3]) - 32) * 4;

    // staging precompute: per-issue global float-offset (per-lane) and LDS
    // slot base (wave-uniform). Dups re-issue p-1's slot (same data, benign).
    int gsrc0[H0ISS], lbase0[H0ISS];
#pragma unroll
    for (int p = 0; p < H0ISS; ++p) {
        int slot = wave + 16 * p; if (slot >= H0SLOTS) slot -= 16;
        int c = slot * 64 + lane;
        int r = frow0(c);
        gsrc0[p]  = r * NDIM + (c - rs0(r)) * 4;
        lbase0[p] = slot * 256;
    }
    int gsrc1[H1ISS], lbase1[H1ISS];
#pragma unroll
    for (int p = 0; p < H1ISS; ++p) {
        int slot = wave + 16 * p; if (slot >= H1SLOTS) slot -= 16;
        int c = slot * 64 + lane;
        int r = frow1(c);
        gsrc1[p]  = r * NDIM + 128 + (c - rs1(r)) * 4;
        lbase1[p] = H0C * 4 + slot * 256;
    }

    // zero x state
    if (T < 2 * NDIM) smem[XSOFF + T] = 0.f;

    // prologue: stage A_0, full drain
    {
        const float* As = A;
#pragma unroll
        for (int p = 0; p < H0ISS; ++p) gload_lds16(As + gsrc0[p], Ab + lbase0[p]);
#pragma unroll
        for (int p = 0; p < H1ISS; ++p) gload_lds16(As + gsrc1[p], Ab + lbase1[p]);
    }
    asm volatile("s_waitcnt vmcnt(0) lgkmcnt(0)" ::: "memory");
    __builtin_amdgcn_s_barrier();

    for (int t = 0; t < LSTEPS; ++t) {
        float* xc = smem + XSOFF + ((t & 1) ? NDIM : 0);
        float* xn = smem + XSOFF + ((t & 1) ? 0 : NDIM);
        const float* As = A + (size_t)((t + 1 < LSTEPS) ? t + 1 : t) * (NDIM * NDIM);

        // phase-0 x reads
        const f32x4 xv0 = *(const f32x4*)&xc[s * 4];
        const f32x4 xv1 = *(const f32x4*)&xc[64 + s * 4];

        float acc[4] = {0.f, 0.f, 0.f, 0.f};
        // phase 0: m = s and m = 16+s over 4 rows (masked by triangle)
#pragma unroll
        for (int i = 0; i < 4; ++i) {
            if (s <= mmax[i]) {
                const f32x4 a = *(const f32x4*)&Ab[a0base[i] + s * 4];
                acc[i] = fmaf(a[0], xv0[0], acc[i]);
                acc[i] = fmaf(a[1], xv0[1], acc[i]);
                acc[i] = fmaf(a[2], xv0[2], acc[i]);
                acc[i] = fmaf(a[3], xv0[3], acc[i]);
            }
        }
#pragma unroll
        for (int i = 0; i < 4; ++i) {
            if (16 + s <= mmax[i]) {
                const f32x4 a = *(const f32x4*)&Ab[a0base[i] + (16 + s) * 4];
                acc[i] = fmaf(a[0], xv1[0], acc[i]);
                acc[i] = fmaf(a[1], xv1[1], acc[i]);
                acc[i] = fmaf(a[2], xv1[2], acc[i]);
                acc[i] = fmaf(a[3], xv1[3], acc[i]);
            }
        }

        // H1^t landed (nothing newer in flight here -> vmcnt(0) is exact);
        // then barrier -> all waves' H0^t reads done, all H1^t DMA visible.
        asm volatile("s_waitcnt vmcnt(0)" ::: "memory");
        asm volatile("s_waitcnt lgkmcnt(0)" ::: "memory");
        __builtin_amdgcn_s_barrier();

        // H0 region free -> issue H0^{t+1}
#pragma unroll
        for (int p = 0; p < H0ISS; ++p) gload_lds16(As + gsrc0[p], Ab + lbase0[p]);

        // scalars + coalesced out[t-1] store (each wave: one full 64B line)
        const float scal_in = inp[t * BATCH + b];
        const float scal_b  = Bst[t * NDIM + rowOwn];
        if (t > 0 && lane < 16)
            out[(size_t)(t - 1) * (BATCH * NDIM) + (size_t)b * NDIM + wave * 16 + lane]
                = xc[wave * 16 + lane];

        // phase-1 x reads
        const f32x4 xv2 = *(const f32x4*)&xc[128 + s * 4];
        const f32x4 xv3 = *(const f32x4*)&xc[192 + s * 4];

        // phase 1: m = 32+s and m = 48+s, rows[2..3] only (r >= 128)
#pragma unroll
        for (int i = 2; i < 4; ++i) {
            if (32 + s <= mmax[i]) {
                const f32x4 a = *(const f32x4*)&Ab[a1base[i - 2] + (32 + s) * 4];
                acc[i] = fmaf(a[0], xv2[0], acc[i]);
                acc[i] = fmaf(a[1], xv2[1], acc[i]);
                acc[i] = fmaf(a[2], xv2[2], acc[i]);
                acc[i] = fmaf(a[3], xv2[3], acc[i]);
            }
            if (48 + s <= mmax[i]) {
                const f32x4 a = *(const f32x4*)&Ab[a1base[i - 2] + (48 + s) * 4];
                acc[i] = fmaf(a[0], xv3[0], acc[i]);
                acc[i] = fmaf(a[1], xv3[1], acc[i]);
                acc[i] = fmaf(a[2], xv3[2], acc[i]);
                acc[i] = fmaf(a[3], xv3[3], acc[i]);
            }
        }

        // all waves done with H1^t reads -> barrier -> issue H1^{t+1}
        asm volatile("s_waitcnt lgkmcnt(0)" ::: "memory");
        __builtin_amdgcn_s_barrier();
#pragma unroll
        for (int p = 0; p < H1ISS; ++p) gload_lds16(As + gsrc1[p], Ab + lbase1[p]);

        // butterfly: sum 16 k-segments, redistribute to (rowOwn)
        const float c0 = (sel0 ? acc[1] : acc[0]) + __shfl_xor(sel0 ? acc[0] : acc[1], 1);
        const float c1 = (sel0 ? acc[3] : acc[2]) + __shfl_xor(sel0 ? acc[2] : acc[3], 1);
        float d = (sel1 ? c1 : c0) + __shfl_xor(sel1 ? c0 : c1, 2);
        d += __shfl_xor(d, 4);
        d += __shfl_xor(d, 8);
        const float v = fmaf(scal_in, scal_b, d);
        if (writer) xn[rowOwn] = v;

        // H0^{t+1} landed (newest 3 in flight = H1^{t+1}); xs visible; barrier.
        asm volatile("s_waitcnt vmcnt(3)" ::: "memory");
        asm volatile("s_waitcnt lgkmcnt(0)" ::: "memory");
        __builtin_amdgcn_s_barrier();
    }

    // final row: x_{L-1} lives in xs[0] (L even)
    if (lane < 16)
        out[(size_t)(LSTEPS - 1) * (BATCH * NDIM) + (size_t)b * NDIM + wave * 16 + lane]
            = smem[XSOFF + wave * 16 + lane];
}

extern "C" void kernel_launch(void* const* d_in, const int* in_sizes, int n_in,
                              void* d_out, int out_size, void* d_ws, size_t ws_size,
                              hipStream_t stream) {
    const float* inp = (const float*)d_in[0];  // (L, BATCH) f32
    const float* A   = (const float*)d_in[1];  // (L, N, N)  f32
    const float* Bst = (const float*)d_in[2];  // (L, N)     f32
    float* out = (float*)d_out;                // (L, BATCH, N) f32
    (void)hipFuncSetAttribute((const void*)hippo_scan,
                              hipFuncAttributeMaxDynamicSharedMemorySize, SMEM_BYTES);
    hipLaunchKernelGGL(hippo_scan, dim3(NWG), dim3(THREADS), SMEM_BYTES, stream,
                       inp, A, Bst, out);
}